// Round 7
// baseline (313.787 us; speedup 1.0000x reference)
//
#include <hip/hip_runtime.h>
#include <hip/hip_bf16.h>
#include <math.h>

// ---------- constants ----------
#define BB 2
#define TT 2048
#define DMODEL 2048
#define NH 16
#define NKV 4
#define DH 128
#define NQKV 3072            // 2048 + 512 + 512
#define MM (BB*TT)           // 4096

typedef unsigned short u16;
typedef unsigned int u32;

typedef __bf16 bf16x8 __attribute__((ext_vector_type(8)));
typedef __bf16 bf16x4 __attribute__((ext_vector_type(4)));
typedef short short4v __attribute__((ext_vector_type(4)));
typedef float f32x4 __attribute__((ext_vector_type(4)));

__device__ __forceinline__ u16 f2b(float f) {
  union { float f; u32 u; } v; v.f = f;
  u32 r = v.u + 0x7fffu + ((v.u >> 16) & 1u);
  return (u16)(r >> 16);
}
__device__ __forceinline__ float b2f(u16 h) {
  union { u32 u; float f; } v; v.u = ((u32)h) << 16;
  return v.f;
}
__device__ __forceinline__ u32 pack2bf(float x, float y) {
  union { float f; u32 u; } a, b; a.f = x; b.f = y;
  return ((a.u + 0x8000u) >> 16) | ((b.u + 0x8000u) & 0xffff0000u);
}

// async global->LDS, 16B per lane
__device__ __forceinline__ void gload16(const void* g, void* l) {
  __builtin_amdgcn_global_load_lds(
      (const __attribute__((address_space(1))) unsigned int*)g,
      (__attribute__((address_space(3))) unsigned int*)l, 16, 0, 0);
}

__device__ __forceinline__ float fast_exp2(float x) {
#if __has_builtin(__builtin_amdgcn_exp2f)
  return __builtin_amdgcn_exp2f(x);
#else
  return __expf(x * 0.6931471805599453f);
#endif
}

// 16x16x16 bf16 MFMA with fallback chain
__device__ __forceinline__ f32x4 mfma16(bf16x4 a, bf16x4 b, f32x4 c) {
#if __has_builtin(__builtin_amdgcn_mfma_f32_16x16x16bf16_1k)
  union { bf16x4 b; short4v s; } ua, ub;
  ua.b = a; ub.b = b;
  return __builtin_amdgcn_mfma_f32_16x16x16bf16_1k(ua.s, ub.s, c, 0, 0, 0);
#elif __has_builtin(__builtin_amdgcn_mfma_f32_16x16x16_bf16)
  return __builtin_amdgcn_mfma_f32_16x16x16_bf16(a, b, c, 0, 0, 0);
#else
  asm volatile("v_mfma_f32_16x16x16_bf16 %0, %1, %2, %0"
               : "+v"(c) : "v"(a), "v"(b));
  return c;
#endif
}

// ---------- merged prep: cvt_x + rope table + weight transposes (1 launch) ----------
// grid 11264 x 256:
//   [0, 8192)      cvt_x: fp32 x -> bf16 xb, 4 elems/thread
//   [8192, 8704)   rope table [T][64] (cos,sin) fp32
//   [8704, 11264)  transpose+convert 4 weight mats (2560 = 80 x 32 flattened)
__global__ void prep_kernel(const float* __restrict__ x, u16* __restrict__ xb,
                            float2* __restrict__ rtab,
                            const float* __restrict__ wq, const float* __restrict__ wk,
                            const float* __restrict__ wv, const float* __restrict__ wo,
                            u16* __restrict__ wqkvT, u16* __restrict__ woT) {
  __shared__ u16 t[64][65];
  const int bx = blockIdx.x;
  const int tid = threadIdx.x;
  if (bx < 8192) {
    int i = bx * 256 + tid;                  // 2,097,152 items = (BB*TT*DMODEL)/4
    float4 v = ((const float4*)x)[i];
    u32 lo = (u32)f2b(v.x) | ((u32)f2b(v.y) << 16);
    u32 hi = (u32)f2b(v.z) | ((u32)f2b(v.w) << 16);
    uint2 r; r.x = lo; r.y = hi;
    ((uint2*)xb)[i] = r;
  } else if (bx < 8704) {
    int i = (bx - 8192) * 256 + tid;         // 131072 = T*64
    int tt = i >> 6, d = i & 63;
    float inv = exp2f(-(float)d * 0.31143075889569023f);  // 1e6^(-d/64)
    float th = (float)tt * inv;
    float2 cs; cs.x = cosf(th); cs.y = sinf(th);
    rtab[i] = cs;
  } else {
    int tb = bx - 8704;                      // 0..2559
    int tx = tb % 80, ty = tb / 80;
    const float* src; u16* dst; int srcCols, rowOff, cb;
    if (tx < 32)      { src = wq; dst = wqkvT; srcCols = 2048; rowOff = 0;    cb = tx; }
    else if (tx < 40) { src = wk; dst = wqkvT; srcCols = 512;  rowOff = 2048; cb = tx - 32; }
    else if (tx < 48) { src = wv; dst = wqkvT; srcCols = 512;  rowOff = 2560; cb = tx - 40; }
    else              { src = wo; dst = woT;   srcCols = 2048; rowOff = 0;    cb = tx - 48; }
    int c0 = cb * 64, r0 = ty * 64;
    for (int i = tid; i < 4096; i += 256) {
      int r = i >> 6, c = i & 63;
      t[r][c] = f2b(src[(size_t)(r0 + r) * srcCols + c0 + c]);
    }
    __syncthreads();
    for (int i = tid; i < 4096; i += 256) {
      int n = i >> 6, k = i & 63;
      dst[(size_t)(rowOff + c0 + n) * 2048 + r0 + k] = t[k][n];
    }
  }
}

// ================= fused QKV GEMM: 256x256 tile, 8-phase PIPELINED =================
// (unchanged from R6 -- measured ~70us, neutral vs R1 but keep)

#define BARRIER asm volatile("s_barrier" ::: "memory")

#define STAGE_A(H, KT, RB) do { \
    const u16* g_ = gA + (size_t)(H) * 262144 + (size_t)(KT) * 64; \
    gload16(g_,          sm + (RB) + tid * 8); \
    gload16(g_ + 131072, sm + (RB) + 4096 + tid * 8); \
  } while (0)

#define STAGE_B(H, KT, RB) do { \
    const u16* g_ = gB + (size_t)(H) * 262144 + (size_t)(KT) * 64; \
    gload16(g_,          sm + (RB) + tid * 8); \
    gload16(g_ + 131072, sm + (RB) + 4096 + tid * 8); \
  } while (0)

#define LDA2(DST, BU, MH) do { \
    const u16* ab_ = sm + (BU) + (MH) * 8192 + lra * 64; \
    _Pragma("unroll") \
    for (int mi = 0; mi < 4; mi++) { \
      DST[mi][0] = *(const bf16x8*)&ab_[mi * 1024 + as0]; \
      DST[mi][1] = *(const bf16x8*)&ab_[mi * 1024 + as1]; \
    } \
  } while (0)

#define LDB2(DST, BU, NL) do { \
    const u16* bb_ = sm + (BU) + 16384 + hb * 8192 + lrb * 64; \
    _Pragma("unroll") \
    for (int nj = 0; nj < 2; nj++) { \
      DST[nj][0] = *(const bf16x8*)&bb_[((NL)*2+nj) * 1024 + bs0]; \
      DST[nj][1] = *(const bf16x8*)&bb_[((NL)*2+nj) * 1024 + bs1]; \
    } \
  } while (0)

#define MFMAQ2(AR, BR, MH, NL) do { \
    _Pragma("unroll") \
    for (int mi = 0; mi < 4; mi++) \
      _Pragma("unroll") \
      for (int nj = 0; nj < 2; nj++) { \
        acc[(MH)*4+mi][(NL)*2+nj] = __builtin_amdgcn_mfma_f32_16x16x32_bf16( \
            AR[mi][0], BR[nj][0], acc[(MH)*4+mi][(NL)*2+nj], 0, 0, 0); \
        acc[(MH)*4+mi][(NL)*2+nj] = __builtin_amdgcn_mfma_f32_16x16x32_bf16( \
            AR[mi][1], BR[nj][1], acc[(MH)*4+mi][(NL)*2+nj], 0, 0, 0); \
      } \
  } while (0)

#define TILE4P(BU, OBU, KA1, KN) do { \
    LDB2(b23, BU, 1); \
    STAGE_A(1, KA1, (OBU) + 8192); \
    BARRIER; \
    __builtin_amdgcn_s_setprio(1); MFMAQ2(aA, b01, 0, 0); __builtin_amdgcn_s_setprio(0); \
    BARRIER; \
    LDA2(aB, BU, 1); \
    STAGE_A(0, KN, (BU)); \
    BARRIER; \
    __builtin_amdgcn_s_setprio(1); MFMAQ2(aA, b23, 0, 1); __builtin_amdgcn_s_setprio(0); \
    asm volatile("s_waitcnt vmcnt(4)\n\ts_barrier" ::: "memory"); \
    LDA2(aA, OBU, 0); \
    STAGE_B(0, KN, (BU) + 16384); \
    BARRIER; \
    __builtin_amdgcn_s_setprio(1); MFMAQ2(aB, b01, 1, 0); __builtin_amdgcn_s_setprio(0); \
    BARRIER; \
    LDB2(b01, OBU, 0); \
    STAGE_B(1, KN, (BU) + 24576); \
    BARRIER; \
    __builtin_amdgcn_s_setprio(1); MFMAQ2(aB, b23, 1, 1); __builtin_amdgcn_s_setprio(0); \
    asm volatile("s_waitcnt vmcnt(6)\n\ts_barrier" ::: "memory"); \
  } while (0)

__global__ __launch_bounds__(512, 2) void gemm_qkv_kernel(
    const u16* __restrict__ A, const u16* __restrict__ Bt,
    const float* __restrict__ bq, const float* __restrict__ bk,
    const float* __restrict__ bv, const float2* __restrict__ rtab,
    u16* __restrict__ qb, u16* __restrict__ kb, u16* __restrict__ vt,
    float* __restrict__ outK, float* __restrict__ outV) {
  __shared__ __align__(16) u16 sm[65536];
  const int tid  = threadIdx.x;
  const int lane = tid & 63;
  const int wave = tid >> 6;        // 0..7
  const int wm   = wave >> 2;
  const int wn   = wave & 3;
  const int quad = lane >> 4;
  const int l16  = lane & 15;
  const int m0 = blockIdx.y * 256;
  const int n0 = blockIdx.x * 256;
  const int bx = blockIdx.x;

  const int srow = tid >> 3;
  const int sch  = (tid & 7) ^ (srow & 7);
  const u16* gA = A  + (size_t)(m0 + srow) * 2048 + sch * 8;
  const u16* gB = Bt + (size_t)(n0 + srow) * 2048 + sch * 8;

  const int lra = wm * 64 + l16;
  const int lrb = (wn & 1) * 64 + l16;
  const int hb  = wn >> 1;
  const int as0 = ((quad)     ^ (lra & 7)) << 3;
  const int as1 = ((quad + 4) ^ (lra & 7)) << 3;
  const int bs0 = ((quad)     ^ (lrb & 7)) << 3;
  const int bs1 = ((quad + 4) ^ (lrb & 7)) << 3;

  bf16x8 aA[4][2], aB[4][2], b01[2][2], b23[2][2];
  f32x4 acc[8][4];
  const f32x4 zero = {0.f, 0.f, 0.f, 0.f};
#pragma unroll
  for (int i = 0; i < 8; i++)
#pragma unroll
    for (int j = 0; j < 4; j++) acc[i][j] = zero;

  STAGE_A(0, 0, 0);
  STAGE_B(0, 0, 16384);
  STAGE_B(1, 0, 24576);
  STAGE_A(1, 0, 8192);
  STAGE_A(0, 1, 32768);
  STAGE_B(0, 1, 32768 + 16384);
  STAGE_B(1, 1, 32768 + 24576);
  asm volatile("s_waitcnt vmcnt(6)\n\ts_barrier" ::: "memory");

  LDA2(aA, 0, 0);
  LDB2(b01, 0, 0);

#pragma unroll 1
  for (int it2 = 0; it2 < 16; ++it2) {
    const int ka1 = (2 * it2 + 1) & 31;
    const int kn0 = (2 * it2 + 2) & 31;
    const int kn1 = (2 * it2 + 3) & 31;
    TILE4P(0,     32768, ka1, kn0);
    TILE4P(32768, 0,     kn0, kn1);
  }

  asm volatile("s_waitcnt vmcnt(0)\n\ts_barrier" ::: "memory");

  const int cls = (bx < 8) ? 0 : ((bx < 10) ? 1 : 2);
#pragma unroll
  for (int nf = 0; nf < 4; nf++) {
    int col = wn * 64 + nf * 16 + l16;
    int gcol = n0 + col;
    float bval = (cls == 0) ? bq[gcol] : ((cls == 1) ? bk[gcol - 2048] : bv[gcol - 2560]);
#pragma unroll
    for (int mh = 0; mh < 2; mh++)
#pragma unroll
      for (int mi = 0; mi < 4; mi++)
#pragma unroll
        for (int r = 0; r < 4; r++) {
          int row = mh * 128 + wm * 64 + mi * 16 + quad * 4 + r;
          int ci = (row * 256 + col) ^ ((row & 7) << 3);
          sm[ci] = f2b(acc[mh * 4 + mi][nf][r] + bval);
        }
  }
  __syncthreads();

  const int bidx = m0 >> 11;
  const int trow0 = m0 & 2047;

  if (cls < 2) {
    const int isQ = (cls == 0);
#pragma unroll
    for (int itq = 0; itq < 8; itq++) {
      int id = tid + itq * 512;
      int lh = id >> 11;
      int rem = id & 2047;
      int row = rem >> 3, oc = rem & 7;
      int t = trow0 + row;
      int rl = t & 63, ttile = t >> 6;
      int sw = (row & 7) << 3;
      int i0 = (row * 256 + lh * 128 + oc * 8);
      uint4 lo = *(const uint4*)&sm[i0 ^ sw];
      uint4 hi = *(const uint4*)&sm[(i0 + 64) ^ sw];
      const u16* plo = (const u16*)&lo;
      const u16* phi = (const u16*)&hi;
      u16 y1[8], y2[8];
      float f1[8], f2v[8];
#pragma unroll
      for (int j = 0; j < 8; j++) {
        float2 cs = rtab[(t << 6) + oc * 8 + j];
        float x1 = b2f(plo[j]), x2 = b2f(phi[j]);
        f1[j]  = cs.x * x1 - cs.y * x2;
        f2v[j] = cs.x * x2 + cs.y * x1;
        y1[j] = f2b(f1[j]);
        y2[j] = f2b(f2v[j]);
      }
      if (isQ) {
        int hh = bx * 2 + lh;
        size_t tb = ((size_t)(bidx * NH + hh) * 32 + ttile) * 8192;
        *(uint4*)&qb[tb + (size_t)((oc)     * 64 + rl) * 8] = *(const uint4*)y1;
        *(uint4*)&qb[tb + (size_t)((oc + 8) * 64 + rl) * 8] = *(const uint4*)y2;
      } else {
        int hh = bx * 2 + lh - 16;
        size_t tb = ((size_t)(bidx * NKV + hh) * 32 + ttile) * 8192;
        *(uint4*)&kb[tb + (size_t)((oc)     * 64 + rl) * 8] = *(const uint4*)y1;
        *(uint4*)&kb[tb + (size_t)((oc + 8) * 64 + rl) * 8] = *(const uint4*)y2;
        size_t base = ((size_t)(bidx * NKV + hh) * TT + t) * DH + oc * 8;
        *(float4*)&outK[base]          = *(const float4*)&f1[0];
        *(float4*)&outK[base + 4]      = *(const float4*)&f1[4];
        *(float4*)&outK[base + 64]     = *(const float4*)&f2v[0];
        *(float4*)&outK[base + 64 + 4] = *(const float4*)&f2v[4];
      }
    }
  } else {
#pragma unroll
    for (int itv = 0; itv < 16; itv++) {
      int id = tid + itv * 512;
      int lh = id >> 12;
      int rem = id & 4095;
      int row = rem >> 4, oc = rem & 15;
      int kvh = bx * 2 + lh - 20;
      int i0 = (row * 256 + lh * 128 + oc * 8) ^ ((row & 7) << 3);
      uint4 v = *(const uint4*)&sm[i0];
      const u16* pv = (const u16*)&v;
      float f[8];
#pragma unroll
      for (int j = 0; j < 8; j++) f[j] = b2f(pv[j]);
      size_t base = ((size_t)(bidx * NKV + kvh) * TT + trow0 + row) * DH + oc * 8;
      *(float4*)&outV[base]     = *(const float4*)&f[0];
      *(float4*)&outV[base + 4] = *(const float4*)&f[4];
    }
#pragma unroll
    for (int itv = 0; itv < 16; itv++) {
      int id = tid + itv * 512;
      int lh = id >> 12;
      int rem = id & 4095;
      int st = rem >> 10;
      int rem2 = rem & 1023;
      int chunk = rem2 >> 7, dl = rem2 & 127;
      int m = chunk >> 2, qd = chunk & 3;
      int kvh = bx * 2 + lh - 20;
      u16 tmp[8];
#pragma unroll
      for (int e = 0; e < 8; e++) {
        int srw = (2 * m + (e >> 2)) * 16 + qd * 4 + (e & 3);
        int row = st * 64 + srw;
        int idx = (row * 256 + lh * 128 + dl) ^ ((row & 7) << 3);
        tmp[e] = sm[idx];
      }
      int tt = (trow0 >> 6) + st;
      size_t tilebase = ((size_t)(bidx * NKV + kvh) * 32 + tt) * 8192;
      *(uint4*)&vt[tilebase + (size_t)(chunk * 128 + dl) * 8] = *(const uint4*)tmp;
    }
  }
}

// ---------- output-projection GEMM (pipelined): out[M,2048] fp32 ----------
__global__ __launch_bounds__(256, 3) void gemm_out_kernel(
    const u16* __restrict__ A, const u16* __restrict__ Bt,
    float* __restrict__ Cout, int M, int N, int K) {
  __shared__ __align__(16) u16 smo[16384];
  const int tid  = threadIdx.x;
  const int lane = tid & 63;
  const int wave = tid >> 6;
  const int quad = lane >> 4;
  const int l16  = lane & 15;
  const int m0 = blockIdx.y * 128;
  const int n0 = blockIdx.x * 128;
  const int wrow = (wave >> 1) * 64;
  const int wcol = (wave & 1) * 64;

  f32x4 acc[4][4];
  const f32x4 zero = {0.f, 0.f, 0.f, 0.f};
#pragma unroll
  for (int i = 0; i < 4; i++)
#pragma unroll
    for (int j = 0; j < 4; j++) acc[i][j] = zero;

  const int srow = tid >> 2;
  const int scol = (tid & 3) * 8;
  const u16* ga = A  + (size_t)(m0 + srow) * K + scol;
  const u16* gb = Bt + (size_t)(n0 + srow) * K + scol;

  gload16(ga,                  &smo[tid * 8]);
  gload16(ga + (size_t)64 * K, &smo[2048 + tid * 8]);
  gload16(gb,                  &smo[4096 + tid * 8]);
  gload16(gb + (size_t)64 * K, &smo[6144 + tid * 8]);

  for (int k0 = 0; k0 < K; k0 += 32) {
    const int p = (k0 >> 5) & 1;
    const int kn = (k0 + 32 == K) ? 0 : k0 + 32;
    u16* nb = &smo[(p ^ 1) * 8192];
    gload16(ga + kn,                  nb + tid * 8);
    gload16(ga + kn + (size_t)64 * K, nb + 2048 + tid * 8);
    gload16(gb + kn,                  nb + 4096 + tid * 8);
    gload16(gb + kn + (size_t)64 * K, nb + 6144 + tid * 8);
    asm volatile("s_waitcnt vmcnt(4)\n\ts_barrier" ::: "memory");
    const u16* cb = &smo[p * 8192];
    bf16x8 af[4], bf[4];
#pragma unroll
    for (int mi = 0; mi < 4; mi++)
      af[mi] = *(const bf16x8*)&cb[(wrow + mi * 16 + l16) * 32 + quad * 8];
#pragma unroll
    for (int ni = 0; ni < 4; ni++)
      bf[ni] = *(const bf16x8*)&cb[4096 + (wcol + ni * 16 + l16) * 32 + quad * 8];
    asm volatile("s_waitcnt lgkmcnt(0)\n\ts_barrier" ::: "memory");
#pragma unroll
    for (int mi = 0; mi < 4; mi++)
#pragma unroll
      for (int ni = 0; ni < 4; ni++)
        acc[mi][ni] = __builtin_amdgcn_mfma_f32_16x16x32_bf16(af[mi], bf[ni], acc[mi][ni], 0, 0, 0);
  }
  asm volatile("s_waitcnt vmcnt(0)" ::: "memory");

#pragma unroll
  for (int ni = 0; ni < 4; ni++) {
    int gcol = n0 + wcol + ni * 16 + l16;
#pragma unroll
    for (int mi = 0; mi < 4; mi++) {
#pragma unroll
      for (int r = 0; r < 4; r++) {
        int grow = m0 + wrow + mi * 16 + quad * 4 + r;
        Cout[(size_t)grow * N + gcol] = acc[mi][ni][r];
      }
    }
  }
}

// ---------- flash attention v8: two-half + direct-L2 V (no V staging) ----------
// V working set per (b,kv) = 512KB shared by 64 blocks -> L1/L2 resident
// (guide common-mistake #7: staging cache-fit data is pure overhead). PV reads
// vt directly from global; removes V-DMA, the mid-iteration vmcnt(4)+barrier,
// and lets the compiler hoist the 16 independent V loads (addresses depend
// only on kt) above the softmax. K keeps LDS double-buffer (4 waves reuse it).
// Values read and MFMA order identical to v7 -> bit-identical output.
__global__ __launch_bounds__(256, 2) void attn_kernel(
    const u16* __restrict__ Qt, const u16* __restrict__ Kt,
    const u16* __restrict__ Vt, u16* __restrict__ Ob) {
  __shared__ __align__(16) u16 sm[16384];   // 32KB: 2 K buffers only

  const int bh = blockIdx.y;
  const int b = bh >> 4, h = bh & 15, kv = h >> 2;
  const int tid = threadIdx.x;
  const int lane = tid & 63;
  const int wave = tid >> 6;
  const int quad = lane >> 4;
  const int l16 = lane & 15;

  const u16* qbase = Qt + (size_t)(b * NH + h) * 32 * 8192;
  const u16* kbase = Kt + (size_t)(b * NKV + kv) * 32 * 8192;
  const u16* vbase = Vt + (size_t)(b * NKV + kv) * 32 * 8192;

  const f32x4 zero = {0.f, 0.f, 0.f, 0.f};
  const float SC2 = 0.08838834764831845f * 1.4426950408889634f;  // scale*log2e
  const float NEGINF = -__builtin_inff();

  int par = 0;

#pragma unroll
  for (int pp = 0; pp < 4; pp++)
    gload16(kbase + pp * 2048 + tid * 8, sm + pp * 2048 + tid * 8);

  for (int half = 0; half < 2; ++half) {
    const int qt = half ? (31 - (int)blockIdx.x) : (int)blockIdx.x;
    const int q0 = qt * 64;
    const u16* qtile = qbase + (size_t)qt * 8192;
    const int qrel = wave * 16 + l16;

    bf16x8 qf[4];
#pragma unroll
    for (int kc = 0; kc < 4; kc++)
      qf[kc] = *(const bf16x8*)&qtile[(size_t)((kc * 4 + quad) * 64 + qrel) * 8];

    float mrow = NEGINF, lrow = 0.f;
    f32x4 o[8];
#pragma unroll
    for (int d = 0; d < 8; d++) o[d] = zero;

    for (int kt = 0; kt <= qt; ++kt) {
      u16* kb_c = sm + par * 8192;
      u16* kb_n = sm + (par ^ 1) * 8192;
      const int ktn = (kt < qt) ? kt + 1 : 0;   // dummy refetch keeps counts uniform
      const u16* vsrc = vbase + (size_t)kt * 8192;
      const u16* knxt = kbase + (size_t)ktn * 8192;
#pragma unroll
      for (int pp = 0; pp < 4; pp++)
        gload16(knxt + pp * 2048 + tid * 8, kb_n + pp * 2048 + tid * 8);
      // K(kt) (issued last iter / prologue) resident; 4 newest (K ktn) in flight
      asm volatile("s_waitcnt vmcnt(4)\n\ts_barrier" ::: "memory");

      f32x4 sv[4];
#pragma unroll
      for (int mt = 0; mt < 4; mt++) sv[mt] = zero;
      __builtin_amdgcn_s_setprio(1);
#pragma unroll
      for (int kc = 0; kc < 4; kc++) {
#pragma unroll
        for (int mt = 0; mt < 4; mt++) {
          bf16x8 kf = *(const bf16x8*)&kb_c[(size_t)((kc * 4 + quad) * 64 + mt * 16 + l16) * 8];
          sv[mt] = __builtin_amdgcn_mfma_f32_16x16x32_bf16(kf, qf[kc], sv[mt], 0, 0, 0);
        }
      }
      __builtin_amdgcn_s_setprio(0);

      if (kt == qt) {
#pragma unroll
        for (int mt = 0; mt < 4; mt++)
#pragma unroll
          for (int r = 0; r < 4; r++) {
            int srel = mt * 16 + quad * 4 + r;
            if (srel > qrel) sv[mt][r] = NEGINF;
          }
      }
      float mraw = NEGINF;
#pragma unroll
      for (int mt = 0; mt < 4; mt++)
#pragma unroll
        for (int r = 0; r < 4; r++) mraw = fmaxf(mraw, sv[mt][r]);
      mraw = fmaxf(mraw, __shfl_xor(mraw, 16));
      mraw = fmaxf(mraw, __shfl_xor(mraw, 32));

      // T13 defer-max: skip O-rescale when tile max grew < 8
      bool noresc = __all(mraw <= mrow + 8.0f);
      float mnew = noresc ? mrow : fmaxf(mrow, mraw);
      float msc = mnew * SC2;
      float lsum = 0.f;
#pragma unroll
      for (int mt = 0; mt < 4; mt++) {
#pragma unroll
        for (int r = 0; r < 4; r++) {
          float pe = fast_exp2(__builtin_fmaf(sv[mt][r], SC2, -msc));
          sv[mt][r] = pe;
          lsum += pe;
        }
      }
      if (noresc) {
        lrow += lsum;
      } else {
        float alpha = fast_exp2((mrow - mnew) * SC2);
        mrow = mnew;
        lrow = lrow * alpha + lsum;
#pragma unroll
        for (int dt = 0; dt < 8; dt++) {
          o[dt][0] *= alpha; o[dt][1] *= alpha; o[dt][2] *= alpha; o[dt][3] *= alpha;
        }
      }
      bf16x4 pb[4];
#pragma unroll
      for (int mt = 0; mt < 4; mt++) {
        union { u32 u[2]; bf16x4 v; } pu;
        pu.u[0] = pack2bf(sv[mt][0], sv[mt][1]);
        pu.u[1] = pack2bf(sv[mt][2], sv[mt][3]);
        pb[mt] = pu.v;
      }

      // PV: V fragments straight from global (L1/L2-resident vt tile)
      __builtin_amdgcn_s_setprio(1);
#pragma unroll
      for (int m = 0; m < 2; m++) {
#pragma unroll
        for (int dt = 0; dt < 8; dt++) {
          bf16x8 vf = *(const bf16x8*)&vsrc[(size_t)(((m * 4 + quad) * 128) + dt * 16 + l16) * 8];
          bf16x4 vlo = __builtin_shufflevector(vf, vf, 0, 1, 2, 3);
          bf16x4 vhi = __builtin_shufflevector(vf, vf, 4, 5, 6, 7);
          o[dt] = mfma16(vlo, pb[2 * m],     o[dt]);
          o[dt] = mfma16(vhi, pb[2 * m + 1], o[dt]);
        }
      }
      __builtin_amdgcn_s_setprio(0);
      // protect kb_c from next iteration's DMA overwrite
      asm volatile("s_barrier" ::: "memory");
      par ^= 1;
    }

    lrow += __shfl_xor(lrow, 16);
    lrow += __shfl_xor(lrow, 32);
    float inv = 1.0f / lrow;
    int t = q0 + qrel;
    size_t rowbase = (size_t)(b * TT + t) * DMODEL + h * DH;
#pragma unroll
    for (int dt = 0; dt < 8; dt++) {
      uint2 w;
      w.x = pack2bf(o[dt][0] * inv, o[dt][1] * inv);
      w.y = pack2bf(o[dt][2] * inv, o[dt][3] * inv);
      *(uint2*)&Ob[rowbase + dt * 16 + quad * 4] = w;
    }
  }
  asm volatile("s_waitcnt vmcnt(0)" ::: "memory");   // drain stray prefetch
}

// ---------- launcher ----------
extern "C" void kernel_launch(void* const* d_in, const int* in_sizes, int n_in,
                              void* d_out, int out_size, void* d_ws, size_t ws_size,
                              hipStream_t stream) {
  (void)in_sizes; (void)n_in; (void)out_size; (void)ws_size;
  const float* x  = (const float*)d_in[0];
  const float* wq = (const float*)d_in[1];
  const float* bq = (const float*)d_in[2];
  const float* wk = (const float*)d_in[3];
  const float* bk = (const float*)d_in[4];
  const float* wv = (const float*)d_in[5];
  const float* bv = (const float*)d_in[6];
  const float* wo = (const float*)d_in[7];
  float* out = (float*)d_out;

  char* ws = (char*)d_ws;
  u16*    xb    = (u16*)(ws);                       // 16,777,216 B
  u16*    wqkvT = (u16*)(ws + 16777216);            // 12,582,912
  u16*    woT   = (u16*)(ws + 29360128);            //  8,388,608
  float2* rtab  = (float2*)(ws + 37748736);         //  1,048,576
  u16*    qb    = (u16*)(ws + 38797312);            // 16,777,216 (tiled)
  u16*    kb    = (u16*)(ws + 55574528);            //  4,194,304 (tiled)
  u16*    vt    = (u16*)(ws + 59768832);            //  4,194,304 (tiled, PV-perm)
  u16*    ob    = (u16*)(ws + 63963136);            // 16,777,216  (total ~80.7 MB)

  float* outK = out + (size_t)BB * TT * DMODEL;
  float* outV = outK + (size_t)BB * NKV * TT * DH;

  prep_kernel<<<11264, 256, 0, stream>>>(x, xb, rtab, wq, wk, wv, wo, wqkvT, woT);

  gemm_qkv_kernel<<<dim3(NQKV / 256, MM / 256), 512, 0, stream>>>(
      xb, wqkvT, bq, bk, bv, rtab, qb, kb, vt, outK, outV);

  attn_kernel<<<dim3(16, BB * NH), 256, 0, stream>>>(qb, kb, vt, ob);

  gemm_out_kernel<<<dim3(DMODEL / 128, MM / 128), 256, 0, stream>>>(
      ob, woT, out, MM, DMODEL, DMODEL);
}

// Round 9
// 294.480 us; speedup vs baseline: 1.0656x; 1.0656x over previous
//
#include <hip/hip_runtime.h>
#include <hip/hip_bf16.h>
#include <math.h>

// ---------- constants ----------
#define BB 2
#define TT 2048
#define DMODEL 2048
#define NH 16
#define NKV 4
#define DH 128
#define NQKV 3072            // 2048 + 512 + 512
#define MM (BB*TT)           // 4096

typedef unsigned short u16;
typedef unsigned int u32;

typedef __bf16 bf16x8 __attribute__((ext_vector_type(8)));
typedef __bf16 bf16x4 __attribute__((ext_vector_type(4)));
typedef short short4v __attribute__((ext_vector_type(4)));
typedef float f32x4 __attribute__((ext_vector_type(4)));

__device__ __forceinline__ u16 f2b(float f) {
  union { float f; u32 u; } v; v.f = f;
  u32 r = v.u + 0x7fffu + ((v.u >> 16) & 1u);
  return (u16)(r >> 16);
}
__device__ __forceinline__ float b2f(u16 h) {
  union { u32 u; float f; } v; v.u = ((u32)h) << 16;
  return v.f;
}
__device__ __forceinline__ u32 pack2bf(float x, float y) {
  union { float f; u32 u; } a, b; a.f = x; b.f = y;
  return ((a.u + 0x8000u) >> 16) | ((b.u + 0x8000u) & 0xffff0000u);
}

// async global->LDS, 16B per lane
__device__ __forceinline__ void gload16(const void* g, void* l) {
  __builtin_amdgcn_global_load_lds(
      (const __attribute__((address_space(1))) unsigned int*)g,
      (__attribute__((address_space(3))) unsigned int*)l, 16, 0, 0);
}

__device__ __forceinline__ float fast_exp2(float x) {
#if __has_builtin(__builtin_amdgcn_exp2f)
  return __builtin_amdgcn_exp2f(x);
#else
  return __expf(x * 0.6931471805599453f);
#endif
}

// 16x16x16 bf16 MFMA with fallback chain
__device__ __forceinline__ f32x4 mfma16(bf16x4 a, bf16x4 b, f32x4 c) {
#if __has_builtin(__builtin_amdgcn_mfma_f32_16x16x16bf16_1k)
  union { bf16x4 b; short4v s; } ua, ub;
  ua.b = a; ub.b = b;
  return __builtin_amdgcn_mfma_f32_16x16x16bf16_1k(ua.s, ub.s, c, 0, 0, 0);
#elif __has_builtin(__builtin_amdgcn_mfma_f32_16x16x16_bf16)
  return __builtin_amdgcn_mfma_f32_16x16x16_bf16(a, b, c, 0, 0, 0);
#else
  asm volatile("v_mfma_f32_16x16x16_bf16 %0, %1, %2, %0"
               : "+v"(c) : "v"(a), "v"(b));
  return c;
#endif
}

// ---------- merged prep: cvt_x + rope table + weight transposes (1 launch) ----------
// grid 11264 x 256:
//   [0, 8192)      cvt_x: fp32 x -> bf16 xb, 4 elems/thread
//   [8192, 8704)   rope table [T][64] (cos,sin) fp32
//   [8704, 11264)  transpose+convert 4 weight mats (2560 = 80 x 32 flattened)
__global__ void prep_kernel(const float* __restrict__ x, u16* __restrict__ xb,
                            float2* __restrict__ rtab,
                            const float* __restrict__ wq, const float* __restrict__ wk,
                            const float* __restrict__ wv, const float* __restrict__ wo,
                            u16* __restrict__ wqkvT, u16* __restrict__ woT) {
  __shared__ u16 t[64][65];
  const int bx = blockIdx.x;
  const int tid = threadIdx.x;
  if (bx < 8192) {
    int i = bx * 256 + tid;                  // 2,097,152 items = (BB*TT*DMODEL)/4
    float4 v = ((const float4*)x)[i];
    u32 lo = (u32)f2b(v.x) | ((u32)f2b(v.y) << 16);
    u32 hi = (u32)f2b(v.z) | ((u32)f2b(v.w) << 16);
    uint2 r; r.x = lo; r.y = hi;
    ((uint2*)xb)[i] = r;
  } else if (bx < 8704) {
    int i = (bx - 8192) * 256 + tid;         // 131072 = T*64
    int tt = i >> 6, d = i & 63;
    float inv = exp2f(-(float)d * 0.31143075889569023f);  // 1e6^(-d/64)
    float th = (float)tt * inv;
    float2 cs; cs.x = cosf(th); cs.y = sinf(th);
    rtab[i] = cs;
  } else {
    int tb = bx - 8704;                      // 0..2559
    int tx = tb % 80, ty = tb / 80;
    const float* src; u16* dst; int srcCols, rowOff, cb;
    if (tx < 32)      { src = wq; dst = wqkvT; srcCols = 2048; rowOff = 0;    cb = tx; }
    else if (tx < 40) { src = wk; dst = wqkvT; srcCols = 512;  rowOff = 2048; cb = tx - 32; }
    else if (tx < 48) { src = wv; dst = wqkvT; srcCols = 512;  rowOff = 2560; cb = tx - 40; }
    else              { src = wo; dst = woT;   srcCols = 2048; rowOff = 0;    cb = tx - 48; }
    int c0 = cb * 64, r0 = ty * 64;
    for (int i = tid; i < 4096; i += 256) {
      int r = i >> 6, c = i & 63;
      t[r][c] = f2b(src[(size_t)(r0 + r) * srcCols + c0 + c]);
    }
    __syncthreads();
    for (int i = tid; i < 4096; i += 256) {
      int n = i >> 6, k = i & 63;
      dst[(size_t)(rowOff + c0 + n) * 2048 + r0 + k] = t[k][n];
    }
  }
}

// ================= fused QKV GEMM: 256x256 tile, 8-phase PIPELINED =================
// (unchanged -- measured ~70us on R6's container)

#define BARRIER asm volatile("s_barrier" ::: "memory")

#define STAGE_A(H, KT, RB) do { \
    const u16* g_ = gA + (size_t)(H) * 262144 + (size_t)(KT) * 64; \
    gload16(g_,          sm + (RB) + tid * 8); \
    gload16(g_ + 131072, sm + (RB) + 4096 + tid * 8); \
  } while (0)

#define STAGE_B(H, KT, RB) do { \
    const u16* g_ = gB + (size_t)(H) * 262144 + (size_t)(KT) * 64; \
    gload16(g_,          sm + (RB) + tid * 8); \
    gload16(g_ + 131072, sm + (RB) + 4096 + tid * 8); \
  } while (0)

#define LDA2(DST, BU, MH) do { \
    const u16* ab_ = sm + (BU) + (MH) * 8192 + lra * 64; \
    _Pragma("unroll") \
    for (int mi = 0; mi < 4; mi++) { \
      DST[mi][0] = *(const bf16x8*)&ab_[mi * 1024 + as0]; \
      DST[mi][1] = *(const bf16x8*)&ab_[mi * 1024 + as1]; \
    } \
  } while (0)

#define LDB2(DST, BU, NL) do { \
    const u16* bb_ = sm + (BU) + 16384 + hb * 8192 + lrb * 64; \
    _Pragma("unroll") \
    for (int nj = 0; nj < 2; nj++) { \
      DST[nj][0] = *(const bf16x8*)&bb_[((NL)*2+nj) * 1024 + bs0]; \
      DST[nj][1] = *(const bf16x8*)&bb_[((NL)*2+nj) * 1024 + bs1]; \
    } \
  } while (0)

#define MFMAQ2(AR, BR, MH, NL) do { \
    _Pragma("unroll") \
    for (int mi = 0; mi < 4; mi++) \
      _Pragma("unroll") \
      for (int nj = 0; nj < 2; nj++) { \
        acc[(MH)*4+mi][(NL)*2+nj] = __builtin_amdgcn_mfma_f32_16x16x32_bf16( \
            AR[mi][0], BR[nj][0], acc[(MH)*4+mi][(NL)*2+nj], 0, 0, 0); \
        acc[(MH)*4+mi][(NL)*2+nj] = __builtin_amdgcn_mfma_f32_16x16x32_bf16( \
            AR[mi][1], BR[nj][1], acc[(MH)*4+mi][(NL)*2+nj], 0, 0, 0); \
      } \
  } while (0)

#define TILE4P(BU, OBU, KA1, KN) do { \
    LDB2(b23, BU, 1); \
    STAGE_A(1, KA1, (OBU) + 8192); \
    BARRIER; \
    __builtin_amdgcn_s_setprio(1); MFMAQ2(aA, b01, 0, 0); __builtin_amdgcn_s_setprio(0); \
    BARRIER; \
    LDA2(aB, BU, 1); \
    STAGE_A(0, KN, (BU)); \
    BARRIER; \
    __builtin_amdgcn_s_setprio(1); MFMAQ2(aA, b23, 0, 1); __builtin_amdgcn_s_setprio(0); \
    asm volatile("s_waitcnt vmcnt(4)\n\ts_barrier" ::: "memory"); \
    LDA2(aA, OBU, 0); \
    STAGE_B(0, KN, (BU) + 16384); \
    BARRIER; \
    __builtin_amdgcn_s_setprio(1); MFMAQ2(aB, b01, 1, 0); __builtin_amdgcn_s_setprio(0); \
    BARRIER; \
    LDB2(b01, OBU, 0); \
    STAGE_B(1, KN, (BU) + 24576); \
    BARRIER; \
    __builtin_amdgcn_s_setprio(1); MFMAQ2(aB, b23, 1, 1); __builtin_amdgcn_s_setprio(0); \
    asm volatile("s_waitcnt vmcnt(6)\n\ts_barrier" ::: "memory"); \
  } while (0)

__global__ __launch_bounds__(512, 2) void gemm_qkv_kernel(
    const u16* __restrict__ A, const u16* __restrict__ Bt,
    const float* __restrict__ bq, const float* __restrict__ bk,
    const float* __restrict__ bv, const float2* __restrict__ rtab,
    u16* __restrict__ qb, u16* __restrict__ kb, u16* __restrict__ vt,
    float* __restrict__ outK, float* __restrict__ outV) {
  __shared__ __align__(16) u16 sm[65536];
  const int tid  = threadIdx.x;
  const int lane = tid & 63;
  const int wave = tid >> 6;        // 0..7
  const int wm   = wave >> 2;
  const int wn   = wave & 3;
  const int quad = lane >> 4;
  const int l16  = lane & 15;
  const int m0 = blockIdx.y * 256;
  const int n0 = blockIdx.x * 256;
  const int bx = blockIdx.x;

  const int srow = tid >> 3;
  const int sch  = (tid & 7) ^ (srow & 7);
  const u16* gA = A  + (size_t)(m0 + srow) * 2048 + sch * 8;
  const u16* gB = Bt + (size_t)(n0 + srow) * 2048 + sch * 8;

  const int lra = wm * 64 + l16;
  const int lrb = (wn & 1) * 64 + l16;
  const int hb  = wn >> 1;
  const int as0 = ((quad)     ^ (lra & 7)) << 3;
  const int as1 = ((quad + 4) ^ (lra & 7)) << 3;
  const int bs0 = ((quad)     ^ (lrb & 7)) << 3;
  const int bs1 = ((quad + 4) ^ (lrb & 7)) << 3;

  bf16x8 aA[4][2], aB[4][2], b01[2][2], b23[2][2];
  f32x4 acc[8][4];
  const f32x4 zero = {0.f, 0.f, 0.f, 0.f};
#pragma unroll
  for (int i = 0; i < 8; i++)
#pragma unroll
    for (int j = 0; j < 4; j++) acc[i][j] = zero;

  STAGE_A(0, 0, 0);
  STAGE_B(0, 0, 16384);
  STAGE_B(1, 0, 24576);
  STAGE_A(1, 0, 8192);
  STAGE_A(0, 1, 32768);
  STAGE_B(0, 1, 32768 + 16384);
  STAGE_B(1, 1, 32768 + 24576);
  asm volatile("s_waitcnt vmcnt(6)\n\ts_barrier" ::: "memory");

  LDA2(aA, 0, 0);
  LDB2(b01, 0, 0);

#pragma unroll 1
  for (int it2 = 0; it2 < 16; ++it2) {
    const int ka1 = (2 * it2 + 1) & 31;
    const int kn0 = (2 * it2 + 2) & 31;
    const int kn1 = (2 * it2 + 3) & 31;
    TILE4P(0,     32768, ka1, kn0);
    TILE4P(32768, 0,     kn0, kn1);
  }

  asm volatile("s_waitcnt vmcnt(0)\n\ts_barrier" ::: "memory");

  const int cls = (bx < 8) ? 0 : ((bx < 10) ? 1 : 2);
#pragma unroll
  for (int nf = 0; nf < 4; nf++) {
    int col = wn * 64 + nf * 16 + l16;
    int gcol = n0 + col;
    float bval = (cls == 0) ? bq[gcol] : ((cls == 1) ? bk[gcol - 2048] : bv[gcol - 2560]);
#pragma unroll
    for (int mh = 0; mh < 2; mh++)
#pragma unroll
      for (int mi = 0; mi < 4; mi++)
#pragma unroll
        for (int r = 0; r < 4; r++) {
          int row = mh * 128 + wm * 64 + mi * 16 + quad * 4 + r;
          int ci = (row * 256 + col) ^ ((row & 7) << 3);
          sm[ci] = f2b(acc[mh * 4 + mi][nf][r] + bval);
        }
  }
  __syncthreads();

  const int bidx = m0 >> 11;
  const int trow0 = m0 & 2047;

  if (cls < 2) {
    const int isQ = (cls == 0);
#pragma unroll
    for (int itq = 0; itq < 8; itq++) {
      int id = tid + itq * 512;
      int lh = id >> 11;
      int rem = id & 2047;
      int row = rem >> 3, oc = rem & 7;
      int t = trow0 + row;
      int rl = t & 63, ttile = t >> 6;
      int sw = (row & 7) << 3;
      int i0 = (row * 256 + lh * 128 + oc * 8);
      uint4 lo = *(const uint4*)&sm[i0 ^ sw];
      uint4 hi = *(const uint4*)&sm[(i0 + 64) ^ sw];
      const u16* plo = (const u16*)&lo;
      const u16* phi = (const u16*)&hi;
      u16 y1[8], y2[8];
      float f1[8], f2v[8];
#pragma unroll
      for (int j = 0; j < 8; j++) {
        float2 cs = rtab[(t << 6) + oc * 8 + j];
        float x1 = b2f(plo[j]), x2 = b2f(phi[j]);
        f1[j]  = cs.x * x1 - cs.y * x2;
        f2v[j] = cs.x * x2 + cs.y * x1;
        y1[j] = f2b(f1[j]);
        y2[j] = f2b(f2v[j]);
      }
      if (isQ) {
        int hh = bx * 2 + lh;
        size_t tb = ((size_t)(bidx * NH + hh) * 32 + ttile) * 8192;
        *(uint4*)&qb[tb + (size_t)((oc)     * 64 + rl) * 8] = *(const uint4*)y1;
        *(uint4*)&qb[tb + (size_t)((oc + 8) * 64 + rl) * 8] = *(const uint4*)y2;
      } else {
        int hh = bx * 2 + lh - 16;
        size_t tb = ((size_t)(bidx * NKV + hh) * 32 + ttile) * 8192;
        *(uint4*)&kb[tb + (size_t)((oc)     * 64 + rl) * 8] = *(const uint4*)y1;
        *(uint4*)&kb[tb + (size_t)((oc + 8) * 64 + rl) * 8] = *(const uint4*)y2;
        size_t base = ((size_t)(bidx * NKV + hh) * TT + t) * DH + oc * 8;
        *(float4*)&outK[base]          = *(const float4*)&f1[0];
        *(float4*)&outK[base + 4]      = *(const float4*)&f1[4];
        *(float4*)&outK[base + 64]     = *(const float4*)&f2v[0];
        *(float4*)&outK[base + 64 + 4] = *(const float4*)&f2v[4];
      }
    }
  } else {
#pragma unroll
    for (int itv = 0; itv < 16; itv++) {
      int id = tid + itv * 512;
      int lh = id >> 12;
      int rem = id & 4095;
      int row = rem >> 4, oc = rem & 15;
      int kvh = bx * 2 + lh - 20;
      int i0 = (row * 256 + lh * 128 + oc * 8) ^ ((row & 7) << 3);
      uint4 v = *(const uint4*)&sm[i0];
      const u16* pv = (const u16*)&v;
      float f[8];
#pragma unroll
      for (int j = 0; j < 8; j++) f[j] = b2f(pv[j]);
      size_t base = ((size_t)(bidx * NKV + kvh) * TT + trow0 + row) * DH + oc * 8;
      *(float4*)&outV[base]     = *(const float4*)&f[0];
      *(float4*)&outV[base + 4] = *(const float4*)&f[4];
    }
#pragma unroll
    for (int itv = 0; itv < 16; itv++) {
      int id = tid + itv * 512;
      int lh = id >> 12;
      int rem = id & 4095;
      int st = rem >> 10;
      int rem2 = rem & 1023;
      int chunk = rem2 >> 7, dl = rem2 & 127;
      int m = chunk >> 2, qd = chunk & 3;
      int kvh = bx * 2 + lh - 20;
      u16 tmp[8];
#pragma unroll
      for (int e = 0; e < 8; e++) {
        int srw = (2 * m + (e >> 2)) * 16 + qd * 4 + (e & 3);
        int row = st * 64 + srw;
        int idx = (row * 256 + lh * 128 + dl) ^ ((row & 7) << 3);
        tmp[e] = sm[idx];
      }
      int tt = (trow0 >> 6) + st;
      size_t tilebase = ((size_t)(bidx * NKV + kvh) * 32 + tt) * 8192;
      *(uint4*)&vt[tilebase + (size_t)(chunk * 128 + dl) * 8] = *(const uint4*)tmp;
    }
  }
}

// ---------- output-projection GEMM (pipelined): out[M,2048] fp32 ----------
__global__ __launch_bounds__(256, 3) void gemm_out_kernel(
    const u16* __restrict__ A, const u16* __restrict__ Bt,
    float* __restrict__ Cout, int M, int N, int K) {
  __shared__ __align__(16) u16 smo[16384];
  const int tid  = threadIdx.x;
  const int lane = tid & 63;
  const int wave = tid >> 6;
  const int quad = lane >> 4;
  const int l16  = lane & 15;
  const int m0 = blockIdx.y * 128;
  const int n0 = blockIdx.x * 128;
  const int wrow = (wave >> 1) * 64;
  const int wcol = (wave & 1) * 64;

  f32x4 acc[4][4];
  const f32x4 zero = {0.f, 0.f, 0.f, 0.f};
#pragma unroll
  for (int i = 0; i < 4; i++)
#pragma unroll
    for (int j = 0; j < 4; j++) acc[i][j] = zero;

  const int srow = tid >> 2;
  const int scol = (tid & 3) * 8;
  const u16* ga = A  + (size_t)(m0 + srow) * K + scol;
  const u16* gb = Bt + (size_t)(n0 + srow) * K + scol;

  gload16(ga,                  &smo[tid * 8]);
  gload16(ga + (size_t)64 * K, &smo[2048 + tid * 8]);
  gload16(gb,                  &smo[4096 + tid * 8]);
  gload16(gb + (size_t)64 * K, &smo[6144 + tid * 8]);

  for (int k0 = 0; k0 < K; k0 += 32) {
    const int p = (k0 >> 5) & 1;
    const int kn = (k0 + 32 == K) ? 0 : k0 + 32;
    u16* nb = &smo[(p ^ 1) * 8192];
    gload16(ga + kn,                  nb + tid * 8);
    gload16(ga + kn + (size_t)64 * K, nb + 2048 + tid * 8);
    gload16(gb + kn,                  nb + 4096 + tid * 8);
    gload16(gb + kn + (size_t)64 * K, nb + 6144 + tid * 8);
    asm volatile("s_waitcnt vmcnt(4)\n\ts_barrier" ::: "memory");
    const u16* cb = &smo[p * 8192];
    bf16x8 af[4], bf[4];
#pragma unroll
    for (int mi = 0; mi < 4; mi++)
      af[mi] = *(const bf16x8*)&cb[(wrow + mi * 16 + l16) * 32 + quad * 8];
#pragma unroll
    for (int ni = 0; ni < 4; ni++)
      bf[ni] = *(const bf16x8*)&cb[4096 + (wcol + ni * 16 + l16) * 32 + quad * 8];
    asm volatile("s_waitcnt lgkmcnt(0)\n\ts_barrier" ::: "memory");
#pragma unroll
    for (int mi = 0; mi < 4; mi++)
#pragma unroll
      for (int ni = 0; ni < 4; ni++)
        acc[mi][ni] = __builtin_amdgcn_mfma_f32_16x16x32_bf16(af[mi], bf[ni], acc[mi][ni], 0, 0, 0);
  }
  asm volatile("s_waitcnt vmcnt(0)" ::: "memory");

#pragma unroll
  for (int ni = 0; ni < 4; ni++) {
    int gcol = n0 + wcol + ni * 16 + l16;
#pragma unroll
    for (int mi = 0; mi < 4; mi++) {
#pragma unroll
      for (int r = 0; r < 4; r++) {
        int grow = m0 + wrow + mi * 16 + quad * 4 + r;
        Cout[(size_t)grow * N + gcol] = acc[mi][ni][r];
      }
    }
  }
}

// ---------- flash attention v7 (revert of v8): two-half + LDS V staging ----------
// R7 post-mortem: direct-L2 V dropped VGPR to 64 -> compiler did NOT hoist the
// 16 V loads above softmax; PV ate exposed L2 latency per MFMA pair (72->94us).
// V-staging via DMA prefetches under QK+softmax at zero VGPR cost. This is the
// R6-measured kernel (72.0us), byte-identical.
__global__ __launch_bounds__(256, 2) void attn_kernel(
    const u16* __restrict__ Qt, const u16* __restrict__ Kt,
    const u16* __restrict__ Vt, u16* __restrict__ Ob) {
  __shared__ __align__(16) u16 sm[24576];
  u16* vbuf = sm + 16384;

  const int bh = blockIdx.y;
  const int b = bh >> 4, h = bh & 15, kv = h >> 2;
  const int tid = threadIdx.x;
  const int lane = tid & 63;
  const int wave = tid >> 6;
  const int quad = lane >> 4;
  const int l16 = lane & 15;

  const u16* qbase = Qt + (size_t)(b * NH + h) * 32 * 8192;
  const u16* kbase = Kt + (size_t)(b * NKV + kv) * 32 * 8192;
  const u16* vbase = Vt + (size_t)(b * NKV + kv) * 32 * 8192;

  const f32x4 zero = {0.f, 0.f, 0.f, 0.f};
  const float SC2 = 0.08838834764831845f * 1.4426950408889634f;  // scale*log2e
  const float NEGINF = -__builtin_inff();

  int par = 0;

#pragma unroll
  for (int pp = 0; pp < 4; pp++)
    gload16(kbase + pp * 2048 + tid * 8, sm + pp * 2048 + tid * 8);

  for (int half = 0; half < 2; ++half) {
    const int qt = half ? (31 - (int)blockIdx.x) : (int)blockIdx.x;
    const int q0 = qt * 64;
    const u16* qtile = qbase + (size_t)qt * 8192;
    const int qrel = wave * 16 + l16;

    bf16x8 qf[4];
#pragma unroll
    for (int kc = 0; kc < 4; kc++)
      qf[kc] = *(const bf16x8*)&qtile[(size_t)((kc * 4 + quad) * 64 + qrel) * 8];

    float mrow = NEGINF, lrow = 0.f;
    f32x4 o[8];
#pragma unroll
    for (int d = 0; d < 8; d++) o[d] = zero;

    for (int kt = 0; kt <= qt; ++kt) {
      u16* kb_c = sm + par * 8192;
      u16* kb_n = sm + (par ^ 1) * 8192;
      const int ktn = (kt < qt) ? kt + 1 : 0;
      const u16* vsrc = vbase + (size_t)kt * 8192;
      const u16* knxt = kbase + (size_t)ktn * 8192;
#pragma unroll
      for (int pp = 0; pp < 4; pp++)
        gload16(vsrc + pp * 2048 + tid * 8, vbuf + pp * 2048 + tid * 8);
#pragma unroll
      for (int pp = 0; pp < 4; pp++)
        gload16(knxt + pp * 2048 + tid * 8, kb_n + pp * 2048 + tid * 8);
      asm volatile("s_waitcnt vmcnt(8)\n\ts_barrier" ::: "memory");

      f32x4 sv[4];
#pragma unroll
      for (int mt = 0; mt < 4; mt++) sv[mt] = zero;
      __builtin_amdgcn_s_setprio(1);
#pragma unroll
      for (int kc = 0; kc < 4; kc++) {
#pragma unroll
        for (int mt = 0; mt < 4; mt++) {
          bf16x8 kf = *(const bf16x8*)&kb_c[(size_t)((kc * 4 + quad) * 64 + mt * 16 + l16) * 8];
          sv[mt] = __builtin_amdgcn_mfma_f32_16x16x32_bf16(kf, qf[kc], sv[mt], 0, 0, 0);
        }
      }
      __builtin_amdgcn_s_setprio(0);

      if (kt == qt) {
#pragma unroll
        for (int mt = 0; mt < 4; mt++)
#pragma unroll
          for (int r = 0; r < 4; r++) {
            int srel = mt * 16 + quad * 4 + r;
            if (srel > qrel) sv[mt][r] = NEGINF;
          }
      }
      float mraw = NEGINF;
#pragma unroll
      for (int mt = 0; mt < 4; mt++)
#pragma unroll
        for (int r = 0; r < 4; r++) mraw = fmaxf(mraw, sv[mt][r]);
      mraw = fmaxf(mraw, __shfl_xor(mraw, 16));
      mraw = fmaxf(mraw, __shfl_xor(mraw, 32));

      // T13 defer-max: skip O-rescale when tile max grew < 8
      bool noresc = __all(mraw <= mrow + 8.0f);
      float mnew = noresc ? mrow : fmaxf(mrow, mraw);
      float msc = mnew * SC2;
      float lsum = 0.f;
#pragma unroll
      for (int mt = 0; mt < 4; mt++) {
#pragma unroll
        for (int r = 0; r < 4; r++) {
          float pe = fast_exp2(__builtin_fmaf(sv[mt][r], SC2, -msc));
          sv[mt][r] = pe;
          lsum += pe;
        }
      }
      if (noresc) {
        lrow += lsum;
      } else {
        float alpha = fast_exp2((mrow - mnew) * SC2);
        mrow = mnew;
        lrow = lrow * alpha + lsum;
#pragma unroll
        for (int dt = 0; dt < 8; dt++) {
          o[dt][0] *= alpha; o[dt][1] *= alpha; o[dt][2] *= alpha; o[dt][3] *= alpha;
        }
      }
      bf16x4 pb[4];
#pragma unroll
      for (int mt = 0; mt < 4; mt++) {
        union { u32 u[2]; bf16x4 v; } pu;
        pu.u[0] = pack2bf(sv[mt][0], sv[mt][1]);
        pu.u[1] = pack2bf(sv[mt][2], sv[mt][3]);
        pb[mt] = pu.v;
      }

      asm volatile("s_waitcnt vmcnt(4)\n\ts_barrier" ::: "memory");
      __builtin_amdgcn_s_setprio(1);
#pragma unroll
      for (int m = 0; m < 2; m++) {
#pragma unroll
        for (int dt = 0; dt < 8; dt++) {
          bf16x8 vf = *(const bf16x8*)&vbuf[(size_t)(((m * 4 + quad) * 128) + dt * 16 + l16) * 8];
          bf16x4 vlo = __builtin_shufflevector(vf, vf, 0, 1, 2, 3);
          bf16x4 vhi = __builtin_shufflevector(vf, vf, 4, 5, 6, 7);
          o[dt] = mfma16(vlo, pb[2 * m],     o[dt]);
          o[dt] = mfma16(vhi, pb[2 * m + 1], o[dt]);
        }
      }
      __builtin_amdgcn_s_setprio(0);
      asm volatile("s_barrier" ::: "memory");
      par ^= 1;
    }

    lrow += __shfl_xor(lrow, 16);
    lrow += __shfl_xor(lrow, 32);
    float inv = 1.0f / lrow;
    int t = q0 + qrel;
    size_t rowbase = (size_t)(b * TT + t) * DMODEL + h * DH;
#pragma unroll
    for (int dt = 0; dt < 8; dt++) {
      uint2 w;
      w.x = pack2bf(o[dt][0] * inv, o[dt][1] * inv);
      w.y = pack2bf(o[dt][2] * inv, o[dt][3] * inv);
      *(uint2*)&Ob[rowbase + dt * 16 + quad * 4] = w;
    }
  }
  asm volatile("s_waitcnt vmcnt(0)" ::: "memory");   // drain stray prefetch
}

// ---------- launcher ----------
extern "C" void kernel_launch(void* const* d_in, const int* in_sizes, int n_in,
                              void* d_out, int out_size, void* d_ws, size_t ws_size,
                              hipStream_t stream) {
  (void)in_sizes; (void)n_in; (void)out_size; (void)ws_size;
  const float* x  = (const float*)d_in[0];
  const float* wq = (const float*)d_in[1];
  const float* bq = (const float*)d_in[2];
  const float* wk = (const float*)d_in[3];
  const float* bk = (const float*)d_in[4];
  const float* wv = (const float*)d_in[5];
  const float* bv = (const float*)d_in[6];
  const float* wo = (const float*)d_in[7];
  float* out = (float*)d_out;

  char* ws = (char*)d_ws;
  u16*    xb    = (u16*)(ws);                       // 16,777,216 B
  u16*    wqkvT = (u16*)(ws + 16777216);            // 12,582,912
  u16*    woT   = (u16*)(ws + 29360128);            //  8,388,608
  float2* rtab  = (float2*)(ws + 37748736);         //  1,048,576
  u16*    qb    = (u16*)(ws + 38797312);            // 16,777,216 (tiled)
  u16*    kb    = (u16*)(ws + 55574528);            //  4,194,304 (tiled)
  u16*    vt    = (u16*)(ws + 59768832);            //  4,194,304 (tiled, PV-perm)
  u16*    ob    = (u16*)(ws + 63963136);            // 16,777,216  (total ~80.7 MB)

  float* outK = out + (size_t)BB * TT * DMODEL;
  float* outV = outK + (size_t)BB * NKV * TT * DH;

  prep_kernel<<<11264, 256, 0, stream>>>(x, xb, rtab, wq, wk, wv, wo, wqkvT, woT);

  gemm_qkv_kernel<<<dim3(NQKV / 256, MM / 256), 512, 0, stream>>>(
      xb, wqkvT, bq, bk, bv, rtab, qb, kb, vt, outK, outV);

  attn_kernel<<<dim3(16, BB * NH), 256, 0, stream>>>(qb, kb, vt, ob);

  gemm_out_kernel<<<dim3(DMODEL / 128, MM / 128), 256, 0, stream>>>(
      ob, woT, out, MM, DMODEL, DMODEL);
}